// Round 1
// baseline (1458.086 us; speedup 1.0000x reference)
//
#include <hip/hip_runtime.h>
#include <math.h>

#define B_ 2048
#define T_ 16
#define F_ 512
#define U_ 512
#define M_ 8

typedef _Float16 half8 __attribute__((ext_vector_type(8)));
typedef float f32x4 __attribute__((ext_vector_type(4)));

// ---------------- prep kernels ----------------
__global__ __launch_bounds__(256) void cast_x_kernel(const float* __restrict__ in,
                                                     _Float16* __restrict__ out) {
    long i = (long)blockIdx.x * 256 + threadIdx.x;     // one thread per 8 elements
    const f32x4* p = (const f32x4*)in;
    f32x4 a = p[i * 2], b = p[i * 2 + 1];
    half8 v;
    v[0] = (_Float16)a[0]; v[1] = (_Float16)a[1]; v[2] = (_Float16)a[2]; v[3] = (_Float16)a[3];
    v[4] = (_Float16)b[0]; v[5] = (_Float16)b[1]; v[6] = (_Float16)b[2]; v[7] = (_Float16)b[3];
    ((half8*)out)[i] = v;
}

// Wt[n][k] = (f16) W[k][n];  W is K x N row-major fp32, Wt is N x K row-major f16
__global__ __launch_bounds__(256) void transpose_cast_kernel(const float* __restrict__ W,
                                                             _Float16* __restrict__ Wt,
                                                             int K, int N) {
    __shared__ float tile[32][33];
    int n0 = blockIdx.x * 32, k0 = blockIdx.y * 32;
    int tx = threadIdx.x, ty = threadIdx.y;
    #pragma unroll
    for (int i = 0; i < 32; i += 8)
        tile[ty + i][tx] = W[(long)(k0 + ty + i) * N + n0 + tx];
    __syncthreads();
    #pragma unroll
    for (int i = 0; i < 32; i += 8)
        Wt[(long)(n0 + ty + i) * K + k0 + tx] = (_Float16)tile[tx][ty + i];
}

// ---------------- GEMM: out[m][n] = act( sum_k A[m][k]*Wt[n][k] + bias[n] ) ----------------
// A is split: k < 512 from A0 (stride lda0), k >= 512 from A1 (stride lda1).
template <int BM, int BN, int FM, int FN, bool TANH>
__global__ __launch_bounds__(256) void gemm_f16_kernel(
    const _Float16* __restrict__ A0, long lda0,
    const _Float16* __restrict__ A1, long lda1,
    const _Float16* __restrict__ Wt,                       // N x K row-major f16
    const float* __restrict__ bias0, const float* __restrict__ bias1, int nsplit,
    _Float16* __restrict__ out, long ldo, int K) {
    constexpr int WMs = FM * 16;
    constexpr int WNs = FN * 16;
    constexpr int CH_A = BM * 8 / 256;   // 16B granules per thread for A tile
    constexpr int CH_B = BN * 8 / 256;
    __shared__ _Float16 As[BM * 64];
    __shared__ _Float16 Bs[BN * 64];
    const int tid = threadIdx.x;
    const int lane = tid & 63;
    const int wave = tid >> 6;
    const int wm = wave >> 1, wn = wave & 1;
    const long m0 = (long)blockIdx.y * BM;
    const long n0 = (long)blockIdx.x * BN;

    f32x4 acc[FM][FN] = {};

    const int kTiles = K >> 6;
    for (int kt = 0; kt < kTiles; ++kt) {
        const _Float16* Asrc; long lda; int kofs;
        if (kt < 8) { Asrc = A0; lda = lda0; kofs = kt * 64; }
        else        { Asrc = A1; lda = lda1; kofs = kt * 64 - 512; }
        // stage A tile (BM x 64), XOR-swizzled granules
        #pragma unroll
        for (int c = 0; c < CH_A; ++c) {
            int idx = tid + c * 256;
            int row = idx >> 3, g = idx & 7;
            int gs = g ^ (row & 7);
            half8 v = *(const half8*)(Asrc + (m0 + row) * lda + kofs + g * 8);
            *(half8*)(As + row * 64 + gs * 8) = v;
        }
        // stage B tile (BN x 64) from Wt
        #pragma unroll
        for (int c = 0; c < CH_B; ++c) {
            int idx = tid + c * 256;
            int row = idx >> 3, g = idx & 7;
            int gs = g ^ (row & 7);
            half8 v = *(const half8*)(Wt + (n0 + row) * (long)K + kt * 64 + g * 8);
            *(half8*)(Bs + row * 64 + gs * 8) = v;
        }
        __syncthreads();
        #pragma unroll
        for (int ks = 0; ks < 2; ++ks) {
            half8 af[FM], bf[FN];
            #pragma unroll
            for (int i = 0; i < FM; ++i) {
                int row = wm * WMs + i * 16 + (lane & 15);
                int g = ks * 4 + (lane >> 4);
                int gs = g ^ (row & 7);
                af[i] = *(const half8*)(As + row * 64 + gs * 8);
            }
            #pragma unroll
            for (int j = 0; j < FN; ++j) {
                int row = wn * WNs + j * 16 + (lane & 15);
                int g = ks * 4 + (lane >> 4);
                int gs = g ^ (row & 7);
                bf[j] = *(const half8*)(Bs + row * 64 + gs * 8);
            }
            #pragma unroll
            for (int i = 0; i < FM; ++i)
                #pragma unroll
                for (int j = 0; j < FN; ++j)
                    acc[i][j] = __builtin_amdgcn_mfma_f32_16x16x32_f16(af[i], bf[j], acc[i][j], 0, 0, 0);
        }
        __syncthreads();
    }

    const int r4 = (lane >> 4) * 4;
    const int c16 = lane & 15;
    #pragma unroll
    for (int i = 0; i < FM; ++i) {
        #pragma unroll
        for (int j = 0; j < FN; ++j) {
            #pragma unroll
            for (int r = 0; r < 4; ++r) {
                long m = m0 + wm * WMs + i * 16 + r4 + r;
                long n = n0 + wn * WNs + j * 16 + c16;
                float v = acc[i][j][r];
                v += (n < nsplit) ? bias0[n] : bias1[n - nsplit];
                if (TANH) v = tanhf(v);
                out[m * ldo + n] = (_Float16)v;
            }
        }
    }
}

// ---------------- EW1: r = softmax(-(ln_r - ln_tau)^2), ctx = sum_m r*h_hat ----------------
__global__ __launch_bounds__(256) void ew1_kernel(const _Float16* __restrict__ ln_rs,
                                                  const float* __restrict__ h_hat,
                                                  _Float16* __restrict__ ctx) {
    const float LT = 1.1512925464970228f;   // 0.5*ln(10)
    long idx = (long)blockIdx.x * 256 + threadIdx.x;   // b*512 + u
    long b = idx >> 9;
    int u = (int)(idx & 511);
    half8 lr = *(const half8*)(ln_rs + b * 8192 + u * 8);
    const f32x4* hh = (const f32x4*)(h_hat + idx * 8);
    f32x4 h0 = hh[0], h1 = hh[1];
    float z[8]; float zmax = -1e30f;
    #pragma unroll
    for (int m = 0; m < 8; ++m) {
        float d = (float)lr[m] - (float)m * LT;
        z[m] = -d * d;
        zmax = fmaxf(zmax, z[m]);
    }
    float s = 0.f, cs = 0.f;
    #pragma unroll
    for (int m = 0; m < 8; ++m) {
        float e = __expf(z[m] - zmax);
        s += e;
        cs += e * (m < 4 ? h0[m] : h1[m - 4]);
    }
    ctx[idx] = (_Float16)(cs / s);
}

// ---------------- EW2: s-softmax, h_hat update, hidden, fused out = hidden @ W_o + b_o ----
struct Decay8 { float d[8]; };

__global__ __launch_bounds__(256) void ew2_kernel(const _Float16* __restrict__ ln_rs,
                                                  const _Float16* __restrict__ qbuf,
                                                  float* __restrict__ h_hat,
                                                  _Float16* __restrict__ h_out,
                                                  const float* __restrict__ W_o,
                                                  const float* __restrict__ b_o,
                                                  float* __restrict__ out,
                                                  int t, Decay8 dec) {
    const float LT = 1.1512925464970228f;
    const int b = blockIdx.x, tid = threadIdx.x;
    float po0 = 0.f, po1 = 0.f, po2 = 0.f;
    #pragma unroll
    for (int rep = 0; rep < 2; ++rep) {
        const int u = tid + rep * 256;
        const long bu = (long)b * 512 + u;
        half8 ls = *(const half8*)(ln_rs + (long)b * 8192 + 4096 + u * 8);
        float qv = (float)qbuf[bu];
        f32x4* hh = (f32x4*)(h_hat + bu * 8);
        f32x4 h0 = hh[0], h1 = hh[1];
        float z[8]; float zmax = -1e30f;
        #pragma unroll
        for (int m = 0; m < 8; ++m) {
            float d = (float)ls[m] - (float)m * LT;
            z[m] = -d * d;
            zmax = fmaxf(zmax, z[m]);
        }
        float e[8]; float ssum = 0.f;
        #pragma unroll
        for (int m = 0; m < 8; ++m) { e[m] = __expf(z[m] - zmax); ssum += e[m]; }
        float inv = 1.f / ssum;
        float hval = 0.f;
        #pragma unroll
        for (int m = 0; m < 8; ++m) {
            float sm = e[m] * inv;
            float hv = (m < 4) ? h0[m] : h1[m - 4];
            float hn = ((1.f - sm) * hv + sm * qv) * dec.d[m];
            if (m < 4) h0[m] = hn; else h1[m - 4] = hn;
            hval += hn;
        }
        hh[0] = h0; hh[1] = h1;
        h_out[bu] = (_Float16)hval;
        po0 += hval * W_o[u * 3 + 0];
        po1 += hval * W_o[u * 3 + 1];
        po2 += hval * W_o[u * 3 + 2];
    }
    __shared__ float r0[256], r1[256], r2[256];
    r0[tid] = po0; r1[tid] = po1; r2[tid] = po2;
    __syncthreads();
    #pragma unroll
    for (int s = 128; s > 0; s >>= 1) {
        if (tid < s) { r0[tid] += r0[tid + s]; r1[tid] += r1[tid + s]; r2[tid] += r2[tid + s]; }
        __syncthreads();
    }
    if (tid == 0) {
        long o = ((long)b * T_ + t) * 3;
        out[o + 0] = r0[0] + b_o[0];
        out[o + 1] = r1[0] + b_o[1];
        out[o + 2] = r2[0] + b_o[2];
    }
}

// ---------------- host ----------------
extern "C" void kernel_launch(void* const* d_in, const int* in_sizes, int n_in,
                              void* d_out, int out_size, void* d_ws, size_t ws_size,
                              hipStream_t stream) {
    const float* x   = (const float*)d_in[0];
    const float* W_r = (const float*)d_in[1];
    const float* b_r = (const float*)d_in[2];
    const float* W_q = (const float*)d_in[3];
    const float* b_q = (const float*)d_in[4];
    const float* W_s = (const float*)d_in[5];
    const float* b_s = (const float*)d_in[6];
    const float* W_o = (const float*)d_in[7];
    const float* b_o = (const float*)d_in[8];
    float* out = (float*)d_out;

    char* ws = (char*)d_ws;
    size_t off = 0;
    _Float16* x_h   = (_Float16*)(ws + off); off += (size_t)B_ * T_ * F_ * 2;   // 32 MB
    _Float16* Wrs_t = (_Float16*)(ws + off); off += (size_t)8192 * 1024 * 2;    // 16 MB
    _Float16* Wq_t  = (_Float16*)(ws + off); off += (size_t)512 * 1024 * 2;     // 1 MB
    _Float16* ln_rs = (_Float16*)(ws + off); off += (size_t)B_ * 8192 * 2;      // 32 MB
    float*    h_hat = (float*)   (ws + off); off += (size_t)B_ * U_ * M_ * 4;   // 32 MB
    _Float16* h_h   = (_Float16*)(ws + off); off += (size_t)B_ * U_ * 2;        // 2 MB
    _Float16* ctx_h = (_Float16*)(ws + off); off += (size_t)B_ * U_ * 2;
    _Float16* q_h   = (_Float16*)(ws + off); off += (size_t)B_ * U_ * 2;
    if (ws_size < off) return;   // insufficient workspace: fail visibly

    hipMemsetAsync(h_hat, 0, (size_t)B_ * U_ * M_ * 4, stream);
    hipMemsetAsync(h_h, 0, (size_t)B_ * U_ * 2, stream);

    cast_x_kernel<<<dim3((B_ * T_ * F_) / (256 * 8)), 256, 0, stream>>>(x, x_h);
    transpose_cast_kernel<<<dim3(4096 / 32, 1024 / 32), dim3(32, 8), 0, stream>>>(W_r, Wrs_t, 1024, 4096);
    transpose_cast_kernel<<<dim3(4096 / 32, 1024 / 32), dim3(32, 8), 0, stream>>>(W_s, Wrs_t + (size_t)4096 * 1024, 1024, 4096);
    transpose_cast_kernel<<<dim3(512 / 32, 1024 / 32), dim3(32, 8), 0, stream>>>(W_q, Wq_t, 1024, 512);

    Decay8 dec;
    for (int m = 0; m < 8; ++m) {
        float lt = (float)m * 1.1512925464970228f;
        dec.d[m] = expf(-0.04f / (expf(lt) + 1e-7f));
    }

    for (int t = 0; t < T_; ++t) {
        // ln_rs = [x_t | h] @ [W_r | W_s] + [b_r | b_s]
        gemm_f16_kernel<128, 128, 4, 4, false><<<dim3(8192 / 128, B_ / 128), 256, 0, stream>>>(
            x_h + (long)t * F_, (long)T_ * F_, h_h, U_, Wrs_t,
            b_r, b_s, 4096, ln_rs, 8192, 1024);
        // r-softmax + ctx
        ew1_kernel<<<dim3(B_ * U_ / 256), 256, 0, stream>>>(ln_rs, h_hat, ctx_h);
        // q = tanh([x_t | ctx] @ W_q + b_q)
        gemm_f16_kernel<64, 64, 2, 2, true><<<dim3(512 / 64, B_ / 64), 256, 0, stream>>>(
            x_h + (long)t * F_, (long)T_ * F_, ctx_h, U_, Wq_t,
            b_q, b_q, 512, q_h, 512, 1024);
        // s-softmax, state update, fused output projection
        ew2_kernel<<<dim3(B_), 256, 0, stream>>>(ln_rs, q_h, h_hat, h_h, W_o, b_o, out, t, dec);
    }
    (void)in_sizes; (void)n_in; (void)out_size;
}

// Round 2
// 1451.702 us; speedup vs baseline: 1.0044x; 1.0044x over previous
//
#include <hip/hip_runtime.h>
#include <math.h>

#define B_ 2048
#define T_ 16
#define F_ 512
#define U_ 512
#define M_ 8

typedef _Float16 half8 __attribute__((ext_vector_type(8)));
typedef float f32x4 __attribute__((ext_vector_type(4)));

__device__ __forceinline__ void load_lds16(const _Float16* gsrc, _Float16* lds) {
    __builtin_amdgcn_global_load_lds(
        (const __attribute__((address_space(1))) void*)gsrc,
        (__attribute__((address_space(3))) void*)lds, 16, 0, 0);
}

// ---------------- prep kernels ----------------
__global__ __launch_bounds__(256) void cast_x_kernel(const float* __restrict__ in,
                                                     _Float16* __restrict__ out) {
    long i = (long)blockIdx.x * 256 + threadIdx.x;     // one thread per 8 elements
    const f32x4* p = (const f32x4*)in;
    f32x4 a = p[i * 2], b = p[i * 2 + 1];
    half8 v;
    v[0] = (_Float16)a[0]; v[1] = (_Float16)a[1]; v[2] = (_Float16)a[2]; v[3] = (_Float16)a[3];
    v[4] = (_Float16)b[0]; v[5] = (_Float16)b[1]; v[6] = (_Float16)b[2]; v[7] = (_Float16)b[3];
    ((half8*)out)[i] = v;
}

// Wt[n][k] = (f16) W[k][n];  W is K x N row-major fp32, Wt is N x K row-major f16
__global__ __launch_bounds__(256) void transpose_cast_kernel(const float* __restrict__ W,
                                                             _Float16* __restrict__ Wt,
                                                             int K, int N) {
    __shared__ float tile[32][33];
    int n0 = blockIdx.x * 32, k0 = blockIdx.y * 32;
    int tx = threadIdx.x, ty = threadIdx.y;
    #pragma unroll
    for (int i = 0; i < 32; i += 8)
        tile[ty + i][tx] = W[(long)(k0 + ty + i) * N + n0 + tx];
    __syncthreads();
    #pragma unroll
    for (int i = 0; i < 32; i += 8)
        Wt[(long)(n0 + ty + i) * K + k0 + tx] = (_Float16)tile[tx][ty + i];
}

// ---------------- GEMM: out[m][n] = act( sum_k A[m][k]*Wt[n][k] + bias[n] ) ----------------
// A is split: k < 512 from A0 (stride lda0), k >= 512 from A1 (stride lda1).
// Staging: global_load_lds direct (width 16), pre-swizzled global source granule
// (g_src = g ^ (row&7)), linear LDS dest; reads apply the matching XOR.
template <int BM, int BN, int FM, int FN, bool TANH>
__global__ __launch_bounds__(256) void gemm_f16_kernel(
    const _Float16* __restrict__ A0, long lda0,
    const _Float16* __restrict__ A1, long lda1,
    const _Float16* __restrict__ Wt,                       // N x K row-major f16
    const float* __restrict__ bias0, const float* __restrict__ bias1, int nsplit,
    _Float16* __restrict__ out, long ldo, int K) {
    constexpr int WMs = FM * 16;
    constexpr int WNs = FN * 16;
    constexpr int CH_A = BM * 8 / 256;   // 16B granules per thread for A tile
    constexpr int CH_B = BN * 8 / 256;
    __shared__ __align__(16) _Float16 As[BM * 64];
    __shared__ __align__(16) _Float16 Bs[BN * 64];
    const int tid = threadIdx.x;
    const int lane = tid & 63;
    const int wave = tid >> 6;
    const int wm = wave >> 1, wn = wave & 1;
    const long m0 = (long)blockIdx.y * BM;
    const long n0 = (long)blockIdx.x * BN;

    f32x4 acc[FM][FN] = {};

    const int kTiles = K >> 6;
    for (int kt = 0; kt < kTiles; ++kt) {
        const _Float16* Asrc; long lda; int kofs;
        if (kt < 8) { Asrc = A0; lda = lda0; kofs = kt * 64; }
        else        { Asrc = A1; lda = lda1; kofs = kt * 64 - 512; }
        // stage A tile (BM x 64): LDS slot s of row r <- global granule s^(r&7)
        #pragma unroll
        for (int c = 0; c < CH_A; ++c) {
            int idx = c * 256 + tid;
            int row = idx >> 3, g = idx & 7;
            int gsrc = g ^ (row & 7);
            _Float16* ldsbase = As + (c * 256 + (wave << 6)) * 8;  // wave-uniform; HW adds lane*16B
            load_lds16(Asrc + (m0 + row) * lda + kofs + gsrc * 8, ldsbase);
        }
        // stage B tile (BN x 64) from Wt
        #pragma unroll
        for (int c = 0; c < CH_B; ++c) {
            int idx = c * 256 + tid;
            int row = idx >> 3, g = idx & 7;
            int gsrc = g ^ (row & 7);
            _Float16* ldsbase = Bs + (c * 256 + (wave << 6)) * 8;
            load_lds16(Wt + (n0 + row) * (long)K + kt * 64 + gsrc * 8, ldsbase);
        }
        __syncthreads();
        #pragma unroll
        for (int ks = 0; ks < 2; ++ks) {
            half8 af[FM], bf[FN];
            #pragma unroll
            for (int i = 0; i < FM; ++i) {
                int row = wm * WMs + i * 16 + (lane & 15);
                int g = ks * 4 + (lane >> 4);
                int gs = g ^ (row & 7);
                af[i] = *(const half8*)(As + row * 64 + gs * 8);
            }
            #pragma unroll
            for (int j = 0; j < FN; ++j) {
                int row = wn * WNs + j * 16 + (lane & 15);
                int g = ks * 4 + (lane >> 4);
                int gs = g ^ (row & 7);
                bf[j] = *(const half8*)(Bs + row * 64 + gs * 8);
            }
            #pragma unroll
            for (int i = 0; i < FM; ++i)
                #pragma unroll
                for (int j = 0; j < FN; ++j)
                    acc[i][j] = __builtin_amdgcn_mfma_f32_16x16x32_f16(af[i], bf[j], acc[i][j], 0, 0, 0);
        }
        __syncthreads();
    }

    const int r4 = (lane >> 4) * 4;
    const int c16 = lane & 15;
    #pragma unroll
    for (int i = 0; i < FM; ++i) {
        #pragma unroll
        for (int j = 0; j < FN; ++j) {
            #pragma unroll
            for (int r = 0; r < 4; ++r) {
                long m = m0 + wm * WMs + i * 16 + r4 + r;
                long n = n0 + wn * WNs + j * 16 + c16;
                float v = acc[i][j][r];
                v += (n < nsplit) ? bias0[n] : bias1[n - nsplit];
                if (TANH) v = tanhf(v);
                out[m * ldo + n] = (_Float16)v;
            }
        }
    }
}

// ---------------- EW1: r = softmax(-(ln_r - ln_tau)^2), ctx = sum_m r*h_hat ----------------
__global__ __launch_bounds__(256) void ew1_kernel(const _Float16* __restrict__ ln_rs,
                                                  const float* __restrict__ h_hat,
                                                  _Float16* __restrict__ ctx) {
    const float LT = 1.1512925464970228f;   // 0.5*ln(10)
    long idx = (long)blockIdx.x * 256 + threadIdx.x;   // b*512 + u
    long b = idx >> 9;
    int u = (int)(idx & 511);
    half8 lr = *(const half8*)(ln_rs + b * 8192 + u * 8);
    const f32x4* hh = (const f32x4*)(h_hat + idx * 8);
    f32x4 h0 = hh[0], h1 = hh[1];
    float z[8]; float zmax = -1e30f;
    #pragma unroll
    for (int m = 0; m < 8; ++m) {
        float d = (float)lr[m] - (float)m * LT;
        z[m] = -d * d;
        zmax = fmaxf(zmax, z[m]);
    }
    float s = 0.f, cs = 0.f;
    #pragma unroll
    for (int m = 0; m < 8; ++m) {
        float e = __expf(z[m] - zmax);
        s += e;
        cs += e * (m < 4 ? h0[m] : h1[m - 4]);
    }
    ctx[idx] = (_Float16)(cs / s);
}

// ---------------- EW2: s-softmax, h_hat update, hidden, fused out = hidden @ W_o + b_o ----
struct Decay8 { float d[8]; };

__global__ __launch_bounds__(256) void ew2_kernel(const _Float16* __restrict__ ln_rs,
                                                  const _Float16* __restrict__ qbuf,
                                                  float* __restrict__ h_hat,
                                                  _Float16* __restrict__ h_out,
                                                  const float* __restrict__ W_o,
                                                  const float* __restrict__ b_o,
                                                  float* __restrict__ out,
                                                  int t, Decay8 dec) {
    const float LT = 1.1512925464970228f;
    const int b = blockIdx.x, tid = threadIdx.x;
    float po0 = 0.f, po1 = 0.f, po2 = 0.f;
    #pragma unroll
    for (int rep = 0; rep < 2; ++rep) {
        const int u = tid + rep * 256;
        const long bu = (long)b * 512 + u;
        half8 ls = *(const half8*)(ln_rs + (long)b * 8192 + 4096 + u * 8);
        float qv = (float)qbuf[bu];
        f32x4* hh = (f32x4*)(h_hat + bu * 8);
        f32x4 h0 = hh[0], h1 = hh[1];
        float z[8]; float zmax = -1e30f;
        #pragma unroll
        for (int m = 0; m < 8; ++m) {
            float d = (float)ls[m] - (float)m * LT;
            z[m] = -d * d;
            zmax = fmaxf(zmax, z[m]);
        }
        float e[8]; float ssum = 0.f;
        #pragma unroll
        for (int m = 0; m < 8; ++m) { e[m] = __expf(z[m] - zmax); ssum += e[m]; }
        float inv = 1.f / ssum;
        float hval = 0.f;
        #pragma unroll
        for (int m = 0; m < 8; ++m) {
            float sm = e[m] * inv;
            float hv = (m < 4) ? h0[m] : h1[m - 4];
            float hn = ((1.f - sm) * hv + sm * qv) * dec.d[m];
            if (m < 4) h0[m] = hn; else h1[m - 4] = hn;
            hval += hn;
        }
        hh[0] = h0; hh[1] = h1;
        h_out[bu] = (_Float16)hval;
        po0 += hval * W_o[u * 3 + 0];
        po1 += hval * W_o[u * 3 + 1];
        po2 += hval * W_o[u * 3 + 2];
    }
    __shared__ float r0[256], r1[256], r2[256];
    r0[tid] = po0; r1[tid] = po1; r2[tid] = po2;
    __syncthreads();
    #pragma unroll
    for (int s = 128; s > 0; s >>= 1) {
        if (tid < s) { r0[tid] += r0[tid + s]; r1[tid] += r1[tid + s]; r2[tid] += r2[tid + s]; }
        __syncthreads();
    }
    if (tid == 0) {
        long o = ((long)b * T_ + t) * 3;
        out[o + 0] = r0[0] + b_o[0];
        out[o + 1] = r1[0] + b_o[1];
        out[o + 2] = r2[0] + b_o[2];
    }
}

// ---------------- host ----------------
extern "C" void kernel_launch(void* const* d_in, const int* in_sizes, int n_in,
                              void* d_out, int out_size, void* d_ws, size_t ws_size,
                              hipStream_t stream) {
    const float* x   = (const float*)d_in[0];
    const float* W_r = (const float*)d_in[1];
    const float* b_r = (const float*)d_in[2];
    const float* W_q = (const float*)d_in[3];
    const float* b_q = (const float*)d_in[4];
    const float* W_s = (const float*)d_in[5];
    const float* b_s = (const float*)d_in[6];
    const float* W_o = (const float*)d_in[7];
    const float* b_o = (const float*)d_in[8];
    float* out = (float*)d_out;

    char* ws = (char*)d_ws;
    size_t off = 0;
    _Float16* x_h   = (_Float16*)(ws + off); off += (size_t)B_ * T_ * F_ * 2;   // 32 MB
    _Float16* Wrs_t = (_Float16*)(ws + off); off += (size_t)8192 * 1024 * 2;    // 16 MB
    _Float16* Wq_t  = (_Float16*)(ws + off); off += (size_t)512 * 1024 * 2;     // 1 MB
    _Float16* ln_rs = (_Float16*)(ws + off); off += (size_t)B_ * 8192 * 2;      // 32 MB
    float*    h_hat = (float*)   (ws + off); off += (size_t)B_ * U_ * M_ * 4;   // 32 MB
    _Float16* h_h   = (_Float16*)(ws + off); off += (size_t)B_ * U_ * 2;        // 2 MB
    _Float16* ctx_h = (_Float16*)(ws + off); off += (size_t)B_ * U_ * 2;
    _Float16* q_h   = (_Float16*)(ws + off); off += (size_t)B_ * U_ * 2;
    if (ws_size < off) return;   // insufficient workspace: fail visibly

    hipMemsetAsync(h_hat, 0, (size_t)B_ * U_ * M_ * 4, stream);
    hipMemsetAsync(h_h, 0, (size_t)B_ * U_ * 2, stream);

    cast_x_kernel<<<dim3((B_ * T_ * F_) / (256 * 8)), 256, 0, stream>>>(x, x_h);
    transpose_cast_kernel<<<dim3(4096 / 32, 1024 / 32), dim3(32, 8), 0, stream>>>(W_r, Wrs_t, 1024, 4096);
    transpose_cast_kernel<<<dim3(4096 / 32, 1024 / 32), dim3(32, 8), 0, stream>>>(W_s, Wrs_t + (size_t)4096 * 1024, 1024, 4096);
    transpose_cast_kernel<<<dim3(512 / 32, 1024 / 32), dim3(32, 8), 0, stream>>>(W_q, Wq_t, 1024, 512);

    Decay8 dec;
    for (int m = 0; m < 8; ++m) {
        float lt = (float)m * 1.1512925464970228f;
        dec.d[m] = expf(-0.04f / (expf(lt) + 1e-7f));
    }

    for (int t = 0; t < T_; ++t) {
        // ln_rs = [x_t | h] @ [W_r | W_s] + [b_r | b_s]
        gemm_f16_kernel<128, 128, 4, 4, false><<<dim3(8192 / 128, B_ / 128), 256, 0, stream>>>(
            x_h + (long)t * F_, (long)T_ * F_, h_h, U_, Wrs_t,
            b_r, b_s, 4096, ln_rs, 8192, 1024);
        // r-softmax + ctx
        ew1_kernel<<<dim3(B_ * U_ / 256), 256, 0, stream>>>(ln_rs, h_hat, ctx_h);
        // q = tanh([x_t | ctx] @ W_q + b_q)
        gemm_f16_kernel<64, 64, 2, 2, true><<<dim3(512 / 64, B_ / 64), 256, 0, stream>>>(
            x_h + (long)t * F_, (long)T_ * F_, ctx_h, U_, Wq_t,
            b_q, b_q, 512, q_h, 512, 1024);
        // s-softmax, state update, fused output projection
        ew2_kernel<<<dim3(B_), 256, 0, stream>>>(ln_rs, q_h, h_hat, h_h, W_o, b_o, out, t, dec);
    }
    (void)in_sizes; (void)n_in; (void)out_size;
}

// Round 3
// 1277.395 us; speedup vs baseline: 1.1415x; 1.1365x over previous
//
#include <hip/hip_runtime.h>
#include <math.h>

#define B_ 2048
#define T_ 16
#define F_ 512
#define U_ 512
#define M_ 8

typedef _Float16 half8 __attribute__((ext_vector_type(8)));
typedef float f32x4 __attribute__((ext_vector_type(4)));

__device__ __forceinline__ void load_lds16(const _Float16* gsrc, _Float16* lds) {
    __builtin_amdgcn_global_load_lds(
        (const __attribute__((address_space(1))) void*)gsrc,
        (__attribute__((address_space(3))) void*)lds, 16, 0, 0);
}

#define BAR() __builtin_amdgcn_s_barrier()
#define LGKM0() do { asm volatile("s_waitcnt lgkmcnt(0)" ::: "memory"); __builtin_amdgcn_sched_barrier(0); } while (0)
#define VMW(n) do { asm volatile("s_waitcnt vmcnt(" #n ")" ::: "memory"); __builtin_amdgcn_sched_barrier(0); } while (0)
#define MFMA16(a, b, c) __builtin_amdgcn_mfma_f32_16x16x32_f16(a, b, c, 0, 0, 0)

// ---------------- prep kernels ----------------
__global__ __launch_bounds__(256) void cast_x_kernel(const float* __restrict__ in,
                                                     _Float16* __restrict__ out) {
    long i = (long)blockIdx.x * 256 + threadIdx.x;
    const f32x4* p = (const f32x4*)in;
    f32x4 a = p[i * 2], b = p[i * 2 + 1];
    half8 v;
    v[0] = (_Float16)a[0]; v[1] = (_Float16)a[1]; v[2] = (_Float16)a[2]; v[3] = (_Float16)a[3];
    v[4] = (_Float16)b[0]; v[5] = (_Float16)b[1]; v[6] = (_Float16)b[2]; v[7] = (_Float16)b[3];
    ((half8*)out)[i] = v;
}

__global__ __launch_bounds__(256) void transpose_cast_kernel(const float* __restrict__ W,
                                                             _Float16* __restrict__ Wt,
                                                             int K, int N) {
    __shared__ float tile[32][33];
    int n0 = blockIdx.x * 32, k0 = blockIdx.y * 32;
    int tx = threadIdx.x, ty = threadIdx.y;
    #pragma unroll
    for (int i = 0; i < 32; i += 8)
        tile[ty + i][tx] = W[(long)(k0 + ty + i) * N + n0 + tx];
    __syncthreads();
    #pragma unroll
    for (int i = 0; i < 32; i += 8)
        Wt[(long)(n0 + ty + i) * K + k0 + tx] = (_Float16)tile[tx][ty + i];
}

// ---------------- GEMM1: 256x256 tile, 8 waves, 8-phase counted-vmcnt pipeline ----------
// out[m][n] = [x_t | h] @ [W_r|W_s]^T(n,k) + bias,  M=2048, N=8192, K=1024 (NT=16 K-tiles)
__global__ __launch_bounds__(512, 2) void gemm1_kernel(
    const _Float16* __restrict__ A0, long lda0,      // x_t  (k<512)
    const _Float16* __restrict__ A1, long lda1,      // h    (k>=512)
    const _Float16* __restrict__ Wt,                  // 8192 x 1024 f16
    const float* __restrict__ bias0, const float* __restrict__ bias1,
    _Float16* __restrict__ out) {
    constexpr int NT = 16;
    __shared__ __align__(16) _Float16 As[2][256 * 64];
    __shared__ __align__(16) _Float16 Bs[2][256 * 64];
    const int tid = threadIdx.x;
    const int lane = tid & 63;
    const int wave = tid >> 6;
    const int wm = wave >> 2, wn = wave & 3;
    const int l15 = lane & 15, lhi = lane >> 4, swz = lane & 7;
    const int g0 = (lhi ^ swz) * 8;           // ks=0 granule offset (f16 units)
    const int g1 = ((lhi + 4) ^ swz) * 8;     // ks=1
    const int srow = tid >> 3;                // staging: row within 64-row round
    const int sg = (tid & 7) ^ (srow & 7);    // staging: pre-swizzled source granule
    const int ldsdst = wave * 64 * 8;         // wave-uniform LDS dest base (f16 units)
    const long m0 = (long)blockIdx.y * 256;
    const long n0 = (long)blockIdx.x * 256;

#define STAGE_A(kt_, buf_, r_) do {                                             \
        int kt__ = (kt_);                                                       \
        const _Float16* s_; long lda_; int kofs_;                               \
        if (kt__ < 8) { s_ = A0; lda_ = lda0; kofs_ = kt__ * 64; }              \
        else          { s_ = A1; lda_ = lda1; kofs_ = kt__ * 64 - 512; }        \
        load_lds16(s_ + (m0 + (r_) * 64 + srow) * lda_ + kofs_ + sg * 8,        \
                   &As[buf_][(r_) * 4096 + ldsdst]);                            \
    } while (0)
#define STAGE_B(kt_, buf_, r_)                                                  \
        load_lds16(Wt + (n0 + (r_) * 64 + srow) * 1024 + (kt_) * 64 + sg * 8,   \
                   &Bs[buf_][(r_) * 4096 + ldsdst])

    f32x4 acc[8][4] = {};

    // Prologue: K0 fully (8 loads, buf0); K1 first 6 rounds (buf1). B-r2/3 of K1
    // are issued at t=0 P0, completing the uniform 8-slot/K-tile pipeline.
    #pragma unroll
    for (int r = 0; r < 4; ++r) STAGE_A(0, 0, r);
    #pragma unroll
    for (int r = 0; r < 4; ++r) STAGE_B(0, 0, r);
    STAGE_A(1, 1, 0); STAGE_A(1, 1, 2);
    STAGE_B(1, 1, 0); STAGE_B(1, 1, 1);
    STAGE_A(1, 1, 1); STAGE_A(1, 1, 3);
    VMW(6);     // own K0 loads retired; barrier makes it global
    BAR();

    #pragma unroll 1
    for (int t = 0; t < NT; ++t) {
        const int cur = t & 1, nxt = cur ^ 1;
        const _Float16* Ac = &As[cur][0];
        const _Float16* Bc = &Bs[cur][0];
        half8 af[4][2], af2[4][2], bf01[2][2], bf23[2][2];

        // ---- P0: C-quadrant (m 0-63, n 0-31) ----
        #pragma unroll
        for (int i = 0; i < 4; ++i) {
            const _Float16* p = Ac + (wm * 128 + i * 16 + l15) * 64;
            af[i][0] = *(const half8*)(p + g0);
            af[i][1] = *(const half8*)(p + g1);
        }
        #pragma unroll
        for (int j = 0; j < 2; ++j) {
            const _Float16* p = Bc + (wn * 64 + j * 16 + l15) * 64;
            bf01[j][0] = *(const half8*)(p + g0);
            bf01[j][1] = *(const half8*)(p + g1);
        }
        if (t + 1 < NT) { STAGE_B(t + 1, nxt, 2); STAGE_B(t + 1, nxt, 3); }
        BAR(); LGKM0();
        __builtin_amdgcn_s_setprio(1);
        #pragma unroll
        for (int i = 0; i < 4; ++i)
            #pragma unroll
            for (int j = 0; j < 2; ++j) {
                acc[i][j] = MFMA16(af[i][0], bf01[j][0], acc[i][j]);
                acc[i][j] = MFMA16(af[i][1], bf01[j][1], acc[i][j]);
            }
        __builtin_amdgcn_s_setprio(0);
        BAR();

        // ---- P1: quadrant (m 0-63, n 32-63); stage A-r0/r2 of t+2 (dead after P0) ----
        #pragma unroll
        for (int j = 0; j < 2; ++j) {
            const _Float16* p = Bc + (wn * 64 + (2 + j) * 16 + l15) * 64;
            bf23[j][0] = *(const half8*)(p + g0);
            bf23[j][1] = *(const half8*)(p + g1);
        }
        if (t + 2 < NT) { STAGE_A(t + 2, cur, 0); STAGE_A(t + 2, cur, 2); }
        BAR(); LGKM0();
        __builtin_amdgcn_s_setprio(1);
        #pragma unroll
        for (int i = 0; i < 4; ++i)
            #pragma unroll
            for (int j = 0; j < 2; ++j) {
                acc[i][2 + j] = MFMA16(af[i][0], bf23[j][0], acc[i][2 + j]);
                acc[i][2 + j] = MFMA16(af[i][1], bf23[j][1], acc[i][2 + j]);
            }
        __builtin_amdgcn_s_setprio(0);
        BAR();

        // ---- P2: quadrant (m 64-127, n 0-31); stage B-r0/r1 of t+2 (B dead after P1) ----
        #pragma unroll
        for (int i = 0; i < 4; ++i) {
            const _Float16* p = Ac + (wm * 128 + (4 + i) * 16 + l15) * 64;
            af2[i][0] = *(const half8*)(p + g0);
            af2[i][1] = *(const half8*)(p + g1);
        }
        if (t + 2 < NT) { STAGE_B(t + 2, cur, 0); STAGE_B(t + 2, cur, 1); }
        BAR(); LGKM0();
        __builtin_amdgcn_s_setprio(1);
        #pragma unroll
        for (int i = 0; i < 4; ++i)
            #pragma unroll
            for (int j = 0; j < 2; ++j) {
                acc[4 + i][j] = MFMA16(af2[i][0], bf01[j][0], acc[4 + i][j]);
                acc[4 + i][j] = MFMA16(af2[i][1], bf01[j][1], acc[4 + i][j]);
            }
        __builtin_amdgcn_s_setprio(0);
        BAR();

        // ---- P3: quadrant (m 64-127, n 32-63); stage A-r1/r3 of t+2 (dead after P2) ----
        if (t + 2 < NT) { STAGE_A(t + 2, cur, 1); STAGE_A(t + 2, cur, 3); }
        __builtin_amdgcn_s_setprio(1);
        #pragma unroll
        for (int i = 0; i < 4; ++i)
            #pragma unroll
            for (int j = 0; j < 2; ++j) {
                acc[4 + i][2 + j] = MFMA16(af2[i][0], bf23[j][0], acc[4 + i][2 + j]);
                acc[4 + i][2 + j] = MFMA16(af2[i][1], bf23[j][1], acc[4 + i][2 + j]);
            }
        __builtin_amdgcn_s_setprio(0);
        // counted wait BEFORE the exit barrier: own W(t+1) loads retired -> after
        // barrier, everyone's are. Steady state 6 outstanding (t+2's p1..p3 stages).
        if (t + 2 < NT)      { VMW(6); }
        else if (t + 1 < NT) { VMW(0); }
        BAR();
    }

    // ---- epilogue ----
    const int r4 = lhi * 4;
    #pragma unroll
    for (int i = 0; i < 8; ++i) {
        #pragma unroll
        for (int j = 0; j < 4; ++j) {
            #pragma unroll
            for (int r = 0; r < 4; ++r) {
                long m = m0 + wm * 128 + i * 16 + r4 + r;
                long n = n0 + wn * 64 + j * 16 + l15;
                float v = acc[i][j][r] + ((n < 4096) ? bias0[n] : bias1[n - 4096]);
                out[m * 8192 + n] = (_Float16)v;
            }
        }
    }
#undef STAGE_A
#undef STAGE_B
}

// ---------------- small GEMM (for q): 64x64 tile, 2-phase (unchanged from R1) -------
template <int BM, int BN, int FM, int FN, bool TANH>
__global__ __launch_bounds__(256) void gemm_f16_kernel(
    const _Float16* __restrict__ A0, long lda0,
    const _Float16* __restrict__ A1, long lda1,
    const _Float16* __restrict__ Wt,
    const float* __restrict__ bias0, const float* __restrict__ bias1, int nsplit,
    _Float16* __restrict__ out, long ldo, int K) {
    constexpr int WMs = FM * 16;
    constexpr int WNs = FN * 16;
    constexpr int CH_A = BM * 8 / 256;
    constexpr int CH_B = BN * 8 / 256;
    __shared__ __align__(16) _Float16 As[BM * 64];
    __shared__ __align__(16) _Float16 Bs[BN * 64];
    const int tid = threadIdx.x;
    const int lane = tid & 63;
    const int wave = tid >> 6;
    const int wm = wave >> 1, wn = wave & 1;
    const long m0 = (long)blockIdx.y * BM;
    const long n0 = (long)blockIdx.x * BN;

    f32x4 acc[FM][FN] = {};

    const int kTiles = K >> 6;
    for (int kt = 0; kt < kTiles; ++kt) {
        const _Float16* Asrc; long lda; int kofs;
        if (kt < 8) { Asrc = A0; lda = lda0; kofs = kt * 64; }
        else        { Asrc = A1; lda = lda1; kofs = kt * 64 - 512; }
        #pragma unroll
        for (int c = 0; c < CH_A; ++c) {
            int idx = c * 256 + tid;
            int row = idx >> 3, g = idx & 7;
            int gsrc = g ^ (row & 7);
            load_lds16(Asrc + (m0 + row) * lda + kofs + gsrc * 8,
                       As + (c * 256 + (wave << 6)) * 8);
        }
        #pragma unroll
        for (int c = 0; c < CH_B; ++c) {
            int idx = c * 256 + tid;
            int row = idx >> 3, g = idx & 7;
            int gsrc = g ^ (row & 7);
            load_lds16(Wt + (n0 + row) * (long)K + kt * 64 + gsrc * 8,
                       Bs + (c * 256 + (wave << 6)) * 8);
        }
        __syncthreads();
        #pragma unroll
        for (int ks = 0; ks < 2; ++ks) {
            half8 af[FM], bf[FN];
            #pragma unroll
            for (int i = 0; i < FM; ++i) {
                int row = wm * WMs + i * 16 + (lane & 15);
                int g = ks * 4 + (lane >> 4);
                int gs = g ^ (row & 7);
                af[i] = *(const half8*)(As + row * 64 + gs * 8);
            }
            #pragma unroll
            for (int j = 0; j < FN; ++j) {
                int row = wn * WNs + j * 16 + (lane & 15);
                int g = ks * 4 + (lane >> 4);
                int gs = g ^ (row & 7);
                bf[j] = *(const half8*)(Bs + row * 64 + gs * 8);
            }
            #pragma unroll
            for (int i = 0; i < FM; ++i)
                #pragma unroll
                for (int j = 0; j < FN; ++j)
                    acc[i][j] = __builtin_amdgcn_mfma_f32_16x16x32_f16(af[i], bf[j], acc[i][j], 0, 0, 0);
        }
        __syncthreads();
    }

    const int r4 = (lane >> 4) * 4;
    const int c16 = lane & 15;
    #pragma unroll
    for (int i = 0; i < FM; ++i) {
        #pragma unroll
        for (int j = 0; j < FN; ++j) {
            #pragma unroll
            for (int r = 0; r < 4; ++r) {
                long m = m0 + wm * WMs + i * 16 + r4 + r;
                long n = n0 + wn * WNs + j * 16 + c16;
                float v = acc[i][j][r];
                v += (n < nsplit) ? bias0[n] : bias1[n - nsplit];
                if (TANH) v = tanhf(v);
                out[m * ldo + n] = (_Float16)v;
            }
        }
    }
}

// ---------------- EW1: r = softmax(-(ln_r - ln_tau)^2), ctx = sum_m r*h_hat ----------
__global__ __launch_bounds__(256) void ew1_kernel(const _Float16* __restrict__ ln_rs,
                                                  const float* __restrict__ h_hat,
                                                  _Float16* __restrict__ ctx) {
    const float LT = 1.1512925464970228f;
    long idx = (long)blockIdx.x * 256 + threadIdx.x;
    long b = idx >> 9;
    int u = (int)(idx & 511);
    half8 lr = *(const half8*)(ln_rs + b * 8192 + u * 8);
    const f32x4* hh = (const f32x4*)(h_hat + idx * 8);
    f32x4 h0 = hh[0], h1 = hh[1];
    float z[8]; float zmax = -1e30f;
    #pragma unroll
    for (int m = 0; m < 8; ++m) {
        float d = (float)lr[m] - (float)m * LT;
        z[m] = -d * d;
        zmax = fmaxf(zmax, z[m]);
    }
    float s = 0.f, cs = 0.f;
    #pragma unroll
    for (int m = 0; m < 8; ++m) {
        float e = __expf(z[m] - zmax);
        s += e;
        cs += e * (m < 4 ? h0[m] : h1[m - 4]);
    }
    ctx[idx] = (_Float16)(cs / s);
}

// ---------------- EW2: s-softmax, h_hat update, fused out = hidden @ W_o + b_o -------
struct Decay8 { float d[8]; };

__global__ __launch_bounds__(256) void ew2_kernel(const _Float16* __restrict__ ln_rs,
                                                  const _Float16* __restrict__ qbuf,
                                                  float* __restrict__ h_hat,
                                                  _Float16* __restrict__ h_out,
                                                  const float* __restrict__ W_o,
                                                  const float* __restrict__ b_o,
                                                  float* __restrict__ out,
                                                  int t, Decay8 dec) {
    const float LT = 1.1512925464970228f;
    const int b = blockIdx.x, tid = threadIdx.x;
    float po0 = 0.f, po1 = 0.f, po2 = 0.f;
    #pragma unroll
    for (int rep = 0; rep < 2; ++rep) {
        const int u = tid + rep * 256;
        const long bu = (long)b * 512 + u;
        half8 ls = *(const half8*)(ln_rs + (long)b * 8192 + 4096 + u * 8);
        float qv = (float)qbuf[bu];
        f32x4* hh = (f32x4*)(h_hat + bu * 8);
        f32x4 h0 = hh[0], h1 = hh[1];
        float z[8]; float zmax = -1e30f;
        #pragma unroll
        for (int m = 0; m < 8; ++m) {
            float d = (float)ls[m] - (float)m * LT;
            z[m] = -d * d;
            zmax = fmaxf(zmax, z[m]);
        }
        float e[8]; float ssum = 0.f;
        #pragma unroll
        for (int m = 0; m < 8; ++m) { e[m] = __expf(z[m] - zmax); ssum += e[m]; }
        float inv = 1.f / ssum;
        float hval = 0.f;
        #pragma unroll
        for (int m = 0; m < 8; ++m) {
            float sm = e[m] * inv;
            float hv = (m < 4) ? h0[m] : h1[m - 4];
            float hn = ((1.f - sm) * hv + sm * qv) * dec.d[m];
            if (m < 4) h0[m] = hn; else h1[m - 4] = hn;
            hval += hn;
        }
        hh[0] = h0; hh[1] = h1;
        h_out[bu] = (_Float16)hval;
        po0 += hval * W_o[u * 3 + 0];
        po1 += hval * W_o[u * 3 + 1];
        po2 += hval * W_o[u * 3 + 2];
    }
    __shared__ float r0[256], r1[256], r2[256];
    r0[tid] = po0; r1[tid] = po1; r2[tid] = po2;
    __syncthreads();
    #pragma unroll
    for (int s = 128; s > 0; s >>= 1) {
        if (tid < s) { r0[tid] += r0[tid + s]; r1[tid] += r1[tid + s]; r2[tid] += r2[tid + s]; }
        __syncthreads();
    }
    if (tid == 0) {
        long o = ((long)b * T_ + t) * 3;
        out[o + 0] = r0[0] + b_o[0];
        out[o + 1] = r1[0] + b_o[1];
        out[o + 2] = r2[0] + b_o[2];
    }
}

// ---------------- host ----------------
extern "C" void kernel_launch(void* const* d_in, const int* in_sizes, int n_in,
                              void* d_out, int out_size, void* d_ws, size_t ws_size,
                              hipStream_t stream) {
    const float* x   = (const float*)d_in[0];
    const float* W_r = (const float*)d_in[1];
    const float* b_r = (const float*)d_in[2];
    const float* W_q = (const float*)d_in[3];
    const float* b_q = (const float*)d_in[4];
    const float* W_s = (const float*)d_in[5];
    const float* b_s = (const float*)d_in[6];
    const float* W_o = (const float*)d_in[7];
    const float* b_o = (const float*)d_in[8];
    float* out = (float*)d_out;

    char* ws = (char*)d_ws;
    size_t off = 0;
    _Float16* x_h   = (_Float16*)(ws + off); off += (size_t)B_ * T_ * F_ * 2;
    _Float16* Wrs_t = (_Float16*)(ws + off); off += (size_t)8192 * 1024 * 2;
    _Float16* Wq_t  = (_Float16*)(ws + off); off += (size_t)512 * 1024 * 2;
    _Float16* ln_rs = (_Float16*)(ws + off); off += (size_t)B_ * 8192 * 2;
    float*    h_hat = (float*)   (ws + off); off += (size_t)B_ * U_ * M_ * 4;
    _Float16* h_h   = (_Float16*)(ws + off); off += (size_t)B_ * U_ * 2;
    _Float16* ctx_h = (_Float16*)(ws + off); off += (size_t)B_ * U_ * 2;
    _Float16* q_h   = (_Float16*)(ws + off); off += (size_t)B_ * U_ * 2;
    if (ws_size < off) return;

    hipMemsetAsync(h_hat, 0, (size_t)B_ * U_ * M_ * 4, stream);
    hipMemsetAsync(h_h, 0, (size_t)B_ * U_ * 2, stream);

    cast_x_kernel<<<dim3((B_ * T_ * F_) / (256 * 8)), 256, 0, stream>>>(x, x_h);
    transpose_cast_kernel<<<dim3(4096 / 32, 1024 / 32), dim3(32, 8), 0, stream>>>(W_r, Wrs_t, 1024, 4096);
    transpose_cast_kernel<<<dim3(4096 / 32, 1024 / 32), dim3(32, 8), 0, stream>>>(W_s, Wrs_t + (size_t)4096 * 1024, 1024, 4096);
    transpose_cast_kernel<<<dim3(512 / 32, 1024 / 32), dim3(32, 8), 0, stream>>>(W_q, Wq_t, 1024, 512);

    Decay8 dec;
    for (int m = 0; m < 8; ++m) {
        float lt = (float)m * 1.1512925464970228f;
        dec.d[m] = expf(-0.04f / (expf(lt) + 1e-7f));
    }

    for (int t = 0; t < T_; ++t) {
        gemm1_kernel<<<dim3(8192 / 256, B_ / 256), 512, 0, stream>>>(
            x_h + (long)t * F_, (long)T_ * F_, h_h, U_, Wrs_t, b_r, b_s, ln_rs);
        ew1_kernel<<<dim3(B_ * U_ / 256), 256, 0, stream>>>(ln_rs, h_hat, ctx_h);
        gemm_f16_kernel<64, 64, 2, 2, true><<<dim3(512 / 64, B_ / 64), 256, 0, stream>>>(
            x_h + (long)t * F_, (long)T_ * F_, ctx_h, U_, Wq_t,
            b_q, b_q, 512, q_h, 512, 1024);
        ew2_kernel<<<dim3(B_), 256, 0, stream>>>(ln_rs, q_h, h_hat, h_h, W_o, b_o, out, t, dec);
    }
    (void)in_sizes; (void)n_in; (void)out_size;
}